// Round 9
// baseline (17569.014 us; speedup 1.0000x reference)
//
#include <hip/hip_runtime.h>
#include <math.h>

#define BATCH 32
#define TLEN  512
#define HID   1024
#define G2    2048   // 2*H

// ---------------------------------------------------------------------------
// Projection GEMM: Cw[t][b][n] = sum_k A[m][k] * W[n][k],  m = b*TLEN + t
// Output permuted to [T][B][2H] so the recurrence reads contiguous slabs.
// ---------------------------------------------------------------------------
__global__ __launch_bounds__(256)
void proj_gemm(const float* __restrict__ A, const float* __restrict__ W,
               float* __restrict__ Cw, int K) {
    __shared__ float As[16][132];
    __shared__ float Bs[16][132];

    const int bm = blockIdx.x;
    const int bn = blockIdx.y;
    const int tid = threadIdx.x;
    const int tx = tid & 15;
    const int ty = tid >> 4;

    const int row0 = bm * 128;
    const int col0 = bn * 128;

    float acc[8][8];
    #pragma unroll
    for (int i = 0; i < 8; ++i)
        #pragma unroll
        for (int j = 0; j < 8; ++j) acc[i][j] = 0.f;

    for (int k0 = 0; k0 < K; k0 += 16) {
        #pragma unroll
        for (int i = 0; i < 2; ++i) {
            int f = tid + i * 256;
            int r = f >> 2;
            int c = (f & 3) * 4;
            float4 va = *(const float4*)&A[(size_t)(row0 + r) * K + k0 + c];
            As[c + 0][r] = va.x; As[c + 1][r] = va.y;
            As[c + 2][r] = va.z; As[c + 3][r] = va.w;
            float4 vb = *(const float4*)&W[(size_t)(col0 + r) * K + k0 + c];
            Bs[c + 0][r] = vb.x; Bs[c + 1][r] = vb.y;
            Bs[c + 2][r] = vb.z; Bs[c + 3][r] = vb.w;
        }
        __syncthreads();

        #pragma unroll
        for (int kk = 0; kk < 16; ++kk) {
            float a[8], b[8];
            #pragma unroll
            for (int i = 0; i < 8; ++i) a[i] = As[kk][ty * 8 + i];
            #pragma unroll
            for (int j = 0; j < 8; ++j) b[j] = Bs[kk][tx * 8 + j];
            #pragma unroll
            for (int i = 0; i < 8; ++i)
                #pragma unroll
                for (int j = 0; j < 8; ++j)
                    acc[i][j] += a[i] * b[j];
        }
        __syncthreads();
    }

    #pragma unroll
    for (int i = 0; i < 8; ++i) {
        int m = row0 + ty * 8 + i;
        int t = m & (TLEN - 1);
        int bb = m >> 9;
        float* dst = &Cw[((size_t)t * BATCH + bb) * G2 + col0 + tx * 8];
        #pragma unroll
        for (int j = 0; j < 8; ++j) dst[j] = acc[i][j];
    }
}

// ---------------------------------------------------------------------------
// Agent-scope (device-coherent) helpers: global_load/store sc0 sc1 (bypass
// L1/L2, hit LLC). No fences, no cache-maintenance ops.
// ---------------------------------------------------------------------------
__device__ __forceinline__ void st_flag(int* p, int v) {
    __hip_atomic_store(p, v, __ATOMIC_RELAXED, __HIP_MEMORY_SCOPE_AGENT);
}
__device__ __forceinline__ int ld_flag(const int* p) {
    return __hip_atomic_load(p, __ATOMIC_RELAXED, __HIP_MEMORY_SCOPE_AGENT);
}
__device__ __forceinline__ void st_h(float* p, float v) {
    __hip_atomic_store(p, v, __ATOMIC_RELAXED, __HIP_MEMORY_SCOPE_AGENT);
}
__device__ __forceinline__ uint64_t ld_h2(const float* p) {
    return __hip_atomic_load((const uint64_t*)p, __ATOMIC_RELAXED,
                             __HIP_MEMORY_SCOPE_AGENT);
}

#define NWG 256
#define FSTRIDE 16   // flags 64 B apart
#define BT 8         // batches per WG
#define JT 16        // j-outputs per WG
#define BHID (BATCH * HID)

__global__ void rec_init(float* h0, int* flags) {
    int i = blockIdx.x * 256 + threadIdx.x;
    if (i < BHID) h0[i] = 0.f;
    if (i < NWG * FSTRIDE) flags[i] = 0;
}

// ---------------------------------------------------------------------------
// Recurrence, group-local sync + register-blocked MAC, sized to fit the
// EMPIRICAL 128-VGPR budget for 512-thread WGs (R7/R8 post-mortem).
// WG wg: bt = wg&3 (4 batch groups x 64 WGs), jb = wg>>2. WG owns batches
// [bt*8,+8) x gates [jb*16,+16) (32 U-rows).
//
// Thread: wv = tid>>6 (k-range of 128), lane = gg*4+kq:
//   gg 0..15 = gate-pair (rows gg*2, gg*2+1), kq 0..3 = k-quarter.
// Thread k-elements: k = wv*128 + kq*4 + i*16, i=0..7  (32 k).
// Per thread: 2 rows x 8 batches x 32 k = 512 FMA, 64 ds_read_b128.
// Register demand: ureg 16xfloat4 (64) + accm[2][8] (16) + hv[4] (16)
// + misc (~15) = ~111 < 128 -> NO SPILL (the R7/R8 failure mode).
// kq folded by 2-round __shfl_xor; red[8][16][2][8] = 8 KB.
// h in 3-deep ring; one flag store + one 64-flag poll per step (R6 scheme).
// ---------------------------------------------------------------------------
__global__ __launch_bounds__(512, 1)
void ligru_rec(const float* __restrict__ w,    // [T][B][2H]
               const float* __restrict__ U,    // [2H][H]
               float* __restrict__ hbuf,       // [3][B][H] ring
               int* __restrict__ flags,        // NWG*FSTRIDE, pre-zeroed
               float* __restrict__ out,        // [B][T][H]
               float* __restrict__ hlast) {    // [B][H]
    __shared__ float hsh[BT * HID];            // 32 KB staged h
    __shared__ float red[8][16][2][8];         // 8 KB wave partials

    const int wg  = blockIdx.x;
    const int tid = threadIdx.x;
    const int bt  = wg & 3;           // group id
    const int jb  = wg >> 2;          // 0..63
    const int j0  = jb * JT;
    const int bg0 = bt * BT;

    const int wv = tid >> 6;          // wave 0..7 (k-range wv*128..+128)
    const int l  = tid & 63;
    const int gg = l >> 2;            // gate-pair: rows gg*2, gg*2+1
    const int kq = l & 3;             // k-quarter within wave
    const int kbase = wv * 128 + kq * 4;

    // ---- U slice -> registers (16 float4 = 64 VGPR, static-indexed)
    float4 ureg[2][8];
    #pragma unroll
    for (int g = 0; g < 2; ++g) {
        int r = gg * 2 + g;           // 0..31
        int urow = (r < 16) ? (j0 + r) : (HID + j0 + (r - 16));
        const float* up = &U[(size_t)urow * HID + kbase];
        #pragma unroll
        for (int i = 0; i < 8; ++i)
            ureg[g][i] = *(const float4*)&up[i * 16];
    }

    float* h_t = hbuf;
    float* h_n = hbuf + BHID;
    float* h_p = hbuf + 2 * BHID;

    for (int t = 0; t < TLEN; ++t) {
        // ---- prefetch w (independent of h; latency hides under poll)
        float wa = 0.f, wz = 0.f;
        if (tid < BT * JT) {          // 128 gate threads
            int bl = tid >> 4;
            int jl = tid & 15;
            const float* wt = &w[((size_t)t * BATCH + bg0 + bl) * G2];
            wa = wt[j0 + jl];
            wz = wt[HID + j0 + jl];
        }

        // ---- wait for the 64 group peers to have published h(t)
        if (t > 0) {
            if (tid < 64) {
                const int* fp = &flags[(bt + (tid << 2)) * FSTRIDE];
                while (ld_flag(fp) < t)
                    __builtin_amdgcn_s_sleep(1);
            }
            __syncthreads();
        }

        // ---- stage h(t)[bg0..bg0+8][:] into LDS (32 KB, coherent)
        {
            const float* src = h_t + (size_t)bg0 * HID;
            #pragma unroll
            for (int c = 0; c < 4; ++c) {
                int off = c * 2048 + tid * 4;
                uint64_t u0 = ld_h2(src + off);
                uint64_t u1 = ld_h2(src + off + 2);
                float4 v;
                ((uint64_t*)&v)[0] = u0;
                ((uint64_t*)&v)[1] = u1;
                *(float4*)&hsh[off] = v;
            }
        }
        __syncthreads();

        // ---- MAC: 2 rows x 8 batches x 32 k per thread; hv in 4-batch halves
        float accm[2][8];
        #pragma unroll
        for (int g = 0; g < 2; ++g)
            #pragma unroll
            for (int b = 0; b < 8; ++b) accm[g][b] = 0.f;
        {
            const float* hp = &hsh[kbase];
            #pragma unroll
            for (int i = 0; i < 8; ++i) {
                {
                    float4 hv[4];
                    #pragma unroll
                    for (int b = 0; b < 4; ++b)
                        hv[b] = *(const float4*)&hp[b * HID + i * 16];
                    #pragma unroll
                    for (int g = 0; g < 2; ++g) {
                        float4 uv = ureg[g][i];
                        #pragma unroll
                        for (int b = 0; b < 4; ++b)
                            accm[g][b] += uv.x * hv[b].x + uv.y * hv[b].y
                                        + uv.z * hv[b].z + uv.w * hv[b].w;
                    }
                }
                __builtin_amdgcn_sched_barrier(0);   // cap hv liveness at 4
                {
                    float4 hv[4];
                    #pragma unroll
                    for (int b = 0; b < 4; ++b)
                        hv[b] = *(const float4*)&hp[(4 + b) * HID + i * 16];
                    #pragma unroll
                    for (int g = 0; g < 2; ++g) {
                        float4 uv = ureg[g][i];
                        #pragma unroll
                        for (int b = 0; b < 4; ++b)
                            accm[g][4 + b] += uv.x * hv[b].x + uv.y * hv[b].y
                                            + uv.z * hv[b].z + uv.w * hv[b].w;
                    }
                }
                __builtin_amdgcn_sched_barrier(0);
            }
        }

        // ---- fold the kq quartet (lane bits 0,1): 2 shfl rounds
        #pragma unroll
        for (int g = 0; g < 2; ++g)
            #pragma unroll
            for (int b = 0; b < 8; ++b) {
                float v = accm[g][b];
                v += __shfl_xor(v, 1);
                v += __shfl_xor(v, 2);
                accm[g][b] = v;
            }
        if (kq == 0) {
            #pragma unroll
            for (int g = 0; g < 2; ++g) {
                *(float4*)&red[wv][gg][g][0] =
                    make_float4(accm[g][0], accm[g][1], accm[g][2], accm[g][3]);
                *(float4*)&red[wv][gg][g][4] =
                    make_float4(accm[g][4], accm[g][5], accm[g][6], accm[g][7]);
            }
        }
        __syncthreads();

        // ---- gates + state update (128 threads)
        if (tid < BT * JT) {
            int bl = tid >> 4;
            int jl = tid & 15;
            float sa = 0.f, sz = 0.f;
            #pragma unroll
            for (int v = 0; v < 8; ++v) {
                sa += red[v][jl >> 1][jl & 1][bl];
                sz += red[v][8 + (jl >> 1)][jl & 1][bl];
            }
            float at = wa + sa;
            float zt = wz + sz;
            zt = 1.f / (1.f + expf(-zt));
            float hc = tanhf(at);
            float hold = hsh[bl * HID + j0 + jl];
            float hnew = zt * hold + (1.f - zt) * hc;
            int bg = bg0 + bl;
            out[((size_t)bg * TLEN + t) * HID + j0 + jl] = hnew;     // plain
            if (t < TLEN - 1) {
                st_h(&h_n[(size_t)bg * HID + j0 + jl], hnew);        // coherent
            } else {
                hlast[(size_t)bg * HID + j0 + jl] = hnew;
            }
        }

        // ---- publish: one store; 3-deep ring makes WAR free
        if (t < TLEN - 1) {
            __syncthreads();   // drains vmcnt -> h stores at LLC
            if (tid == 0) st_flag(&flags[wg * FSTRIDE], t + 1);
        }

        float* tmp = h_t; h_t = h_n; h_n = h_p; h_p = tmp;
    }
}

// ---------------------------------------------------------------------------
extern "C" void kernel_launch(void* const* d_in, const int* in_sizes, int n_in,
                              void* d_out, int out_size, void* d_ws, size_t ws_size,
                              hipStream_t stream) {
    (void)in_sizes; (void)n_in; (void)out_size; (void)ws_size;

    const float* x  = (const float*)d_in[0];
    const float* W0 = (const float*)d_in[1];
    const float* U0 = (const float*)d_in[2];
    const float* W1 = (const float*)d_in[3];
    const float* U1 = (const float*)d_in[4];

    float* out    = (float*)d_out;                              // [B,T,H]
    float* hstack = out + (size_t)BATCH * TLEN * HID;           // [2,B,H]

    int*   flags = (int*)d_ws;                                  // 256*16 ints
    float* hbuf  = (float*)d_ws + NWG * FSTRIDE;                // [3][B][H]
    float* wbuf  = hbuf + 3 * BHID;                             // [T][B][2H]

    dim3 gg(16384 / 128, 2048 / 128);
    int init_blocks = (BHID + 255) / 256;

    // ---- layer 0 ----
    proj_gemm<<<gg, 256, 0, stream>>>(x, W0, wbuf, 512);
    rec_init<<<init_blocks, 256, 0, stream>>>(hbuf, flags);
    ligru_rec<<<dim3(NWG), dim3(512), 0, stream>>>(wbuf, U0, hbuf, flags,
                                                   out, hstack);

    // ---- layer 1 ---- (reads layer-0 output staged in d_out, then overwrites)
    proj_gemm<<<gg, 256, 0, stream>>>(out, W1, wbuf, 1024);
    rec_init<<<init_blocks, 256, 0, stream>>>(hbuf, flags);
    ligru_rec<<<dim3(NWG), dim3(512), 0, stream>>>(wbuf, U1, hbuf, flags,
                                                   out, hstack + BATCH * HID);
}

// Round 10
// 4633.284 us; speedup vs baseline: 3.7919x; 3.7919x over previous
//
#include <hip/hip_runtime.h>
#include <math.h>

#define BATCH 32
#define TLEN  512
#define HID   1024
#define G2    2048   // 2*H

typedef _Float16 half8 __attribute__((ext_vector_type(8)));
typedef float f32x4 __attribute__((ext_vector_type(4)));

// ---------------------------------------------------------------------------
// Projection GEMM: Cw[t][b][n] = sum_k A[m][k] * W[n][k],  m = b*TLEN + t
// Output permuted to [T][B][2H] so the recurrence reads contiguous slabs.
// ---------------------------------------------------------------------------
__global__ __launch_bounds__(256)
void proj_gemm(const float* __restrict__ A, const float* __restrict__ W,
               float* __restrict__ Cw, int K) {
    __shared__ float As[16][132];
    __shared__ float Bs[16][132];

    const int bm = blockIdx.x;
    const int bn = blockIdx.y;
    const int tid = threadIdx.x;
    const int tx = tid & 15;
    const int ty = tid >> 4;

    const int row0 = bm * 128;
    const int col0 = bn * 128;

    float acc[8][8];
    #pragma unroll
    for (int i = 0; i < 8; ++i)
        #pragma unroll
        for (int j = 0; j < 8; ++j) acc[i][j] = 0.f;

    for (int k0 = 0; k0 < K; k0 += 16) {
        #pragma unroll
        for (int i = 0; i < 2; ++i) {
            int f = tid + i * 256;
            int r = f >> 2;
            int c = (f & 3) * 4;
            float4 va = *(const float4*)&A[(size_t)(row0 + r) * K + k0 + c];
            As[c + 0][r] = va.x; As[c + 1][r] = va.y;
            As[c + 2][r] = va.z; As[c + 3][r] = va.w;
            float4 vb = *(const float4*)&W[(size_t)(col0 + r) * K + k0 + c];
            Bs[c + 0][r] = vb.x; Bs[c + 1][r] = vb.y;
            Bs[c + 2][r] = vb.z; Bs[c + 3][r] = vb.w;
        }
        __syncthreads();

        #pragma unroll
        for (int kk = 0; kk < 16; ++kk) {
            float a[8], b[8];
            #pragma unroll
            for (int i = 0; i < 8; ++i) a[i] = As[kk][ty * 8 + i];
            #pragma unroll
            for (int j = 0; j < 8; ++j) b[j] = Bs[kk][tx * 8 + j];
            #pragma unroll
            for (int i = 0; i < 8; ++i)
                #pragma unroll
                for (int j = 0; j < 8; ++j)
                    acc[i][j] += a[i] * b[j];
        }
        __syncthreads();
    }

    #pragma unroll
    for (int i = 0; i < 8; ++i) {
        int m = row0 + ty * 8 + i;
        int t = m & (TLEN - 1);
        int bb = m >> 9;
        float* dst = &Cw[((size_t)t * BATCH + bb) * G2 + col0 + tx * 8];
        #pragma unroll
        for (int j = 0; j < 8; ++j) dst[j] = acc[i][j];
    }
}

// ---------------------------------------------------------------------------
// Agent-scope (device-coherent) helpers: sc0 sc1, bypass L1/per-XCD L2.
// ---------------------------------------------------------------------------
__device__ __forceinline__ void st_flag(int* p, int v) {
    __hip_atomic_store(p, v, __ATOMIC_RELAXED, __HIP_MEMORY_SCOPE_AGENT);
}
__device__ __forceinline__ int ld_flag(const int* p) {
    return __hip_atomic_load(p, __ATOMIC_RELAXED, __HIP_MEMORY_SCOPE_AGENT);
}
__device__ __forceinline__ unsigned long long ld_h2u(const unsigned short* p) {
    return __hip_atomic_load((const unsigned long long*)p, __ATOMIC_RELAXED,
                             __HIP_MEMORY_SCOPE_AGENT);
}
__device__ __forceinline__ void st_h32(unsigned int* p, unsigned int v) {
    __hip_atomic_store(p, v, __ATOMIC_RELAXED, __HIP_MEMORY_SCOPE_AGENT);
}

#define NWG 256
#define FSTRIDE 16   // flags 64 B apart
#define BT 8         // batches per WG
#define JT 16        // a-rows per WG (plus JT z-rows)
#define BHID (BATCH * HID)

__global__ void rec_init(unsigned short* h0, int* flags) {
    int i = blockIdx.x * 256 + threadIdx.x;
    if (i < BHID) h0[i] = 0;              // fp16 +0.0
    if (i < NWG * FSTRIDE) flags[i] = 0;
}

// ---------------------------------------------------------------------------
// MFMA recurrence. WG wg: bt = wg&3 (4 sync groups x 64 WGs), jb = wg>>2.
// WG owns gates rows {j0..j0+15} (a) + {H+j0..H+j0+15} (z), batches
// [bt*8, bt*8+8). gates tile = U_f16[32 rows][K=1024] x h_f16[K][8 batches]
// via mfma_f32_16x16x32_f16: wave wv does K-chunks wv*4..wv*4+3, two M-tiles
// (a,z) sharing each B frag; C-frags cross-wave reduced in 17KB LDS.
//
// A frags (U): fp32->fp16 converted ONCE in prologue, 8 frags = 32 VGPRs
// static (small enough that the allocator keeps them -- the R7-R9 lesson).
// B frags (h): loaded straight from the coherent fp16 h-ring, 8x8B per
// thread per step, in MFMA B layout (lane: batch col = l&7 dup, k
// contiguous). No LDS h staging at all. hold = private register (gate
// thread owns the same (j,b) forever). fp16 error ~1e-3 << 1.98e-2 thresh.
// Sync: R6 scheme -- 3-deep ring, one flag store + one 64-flag poll/step.
// ---------------------------------------------------------------------------
__global__ __launch_bounds__(512, 1)
void ligru_rec(const float* __restrict__ w,        // [T][B][2H] fp32
               const float* __restrict__ U,        // [2H][H] fp32
               unsigned short* __restrict__ hring, // [3][B][H] fp16 ring
               int* __restrict__ flags,            // NWG*FSTRIDE, pre-zeroed
               float* __restrict__ out,            // [B][T][H] fp32
               float* __restrict__ hlast) {        // [B][H] fp32
    __shared__ float red[8][32][17];               // wave C partials (17 KB)

    const int wg  = blockIdx.x;
    const int tid = threadIdx.x;
    const int bt  = wg & 3;
    const int jb  = wg >> 2;          // 0..63
    const int j0  = jb * JT;
    const int bg0 = bt * BT;

    const int wv   = tid >> 6;        // wave 0..7: K-chunks wv*4..wv*4+3
    const int l    = tid & 63;
    const int mrow = l & 15;          // A-frag: M row within tile
    const int kg   = l >> 4;          // k-group 0..3 (8 k each)
    const int bcol = bg0 + (l & 7);   // B-frag batch (cols 8-15 duplicate 0-7)

    // ---- A fragments: U fp32 -> fp16, once (8 frags = 32 VGPRs, static)
    half8 Aa[4], Az[4];
    #pragma unroll
    for (int kc = 0; kc < 4; ++kc) {
        int k0 = (wv * 4 + kc) * 32 + kg * 8;
        const float* pa = &U[(size_t)(j0 + mrow) * HID + k0];
        const float* pz = &U[(size_t)(HID + j0 + mrow) * HID + k0];
        float4 a0 = *(const float4*)pa, a1 = *(const float4*)(pa + 4);
        float4 z0 = *(const float4*)pz, z1 = *(const float4*)(pz + 4);
        half8 va, vz;
        va[0] = (_Float16)a0.x; va[1] = (_Float16)a0.y;
        va[2] = (_Float16)a0.z; va[3] = (_Float16)a0.w;
        va[4] = (_Float16)a1.x; va[5] = (_Float16)a1.y;
        va[6] = (_Float16)a1.z; va[7] = (_Float16)a1.w;
        vz[0] = (_Float16)z0.x; vz[1] = (_Float16)z0.y;
        vz[2] = (_Float16)z0.z; vz[3] = (_Float16)z0.w;
        vz[4] = (_Float16)z1.x; vz[5] = (_Float16)z1.y;
        vz[6] = (_Float16)z1.z; vz[7] = (_Float16)z1.w;
        Aa[kc] = va; Az[kc] = vz;
    }

    unsigned short* h_t = hring;
    unsigned short* h_n = hring + BHID;
    unsigned short* h_p = hring + 2 * BHID;

    // gate-thread coords (tid < 128): jl = gate row 0..15, bl = batch 0..7
    const int jl = tid & 15;
    const int bl = tid >> 4;
    float hprev = 0.f;                // own h[b][j] state, lives in a register

    for (int t = 0; t < TLEN; ++t) {
        // ---- prefetch w (plain cached; latency hides under poll)
        float wa = 0.f, wz = 0.f;
        if (tid < 128) {
            const float* wt = &w[((size_t)t * BATCH + bg0 + bl) * G2];
            wa = wt[j0 + jl];
            wz = wt[HID + j0 + jl];
        }

        // ---- wait for the 64 group peers to have published h(t)
        if (t > 0) {
            if (tid < 64) {
                const int* fp = &flags[((tid << 2) + bt) * FSTRIDE];
                while (ld_flag(fp) < t)
                    __builtin_amdgcn_s_sleep(1);
            }
            __syncthreads();
        }

        // ---- B frags straight from coherent ring + MFMA (8 per wave)
        f32x4 ca = {0.f, 0.f, 0.f, 0.f};
        f32x4 cz = {0.f, 0.f, 0.f, 0.f};
        #pragma unroll
        for (int kc = 0; kc < 4; ++kc) {
            int k0 = (wv * 4 + kc) * 32 + kg * 8;
            const unsigned short* hp = &h_t[(size_t)bcol * HID + k0];
            union { unsigned long long u[2]; half8 h; } B;
            B.u[0] = ld_h2u(hp);
            B.u[1] = ld_h2u(hp + 4);
            ca = __builtin_amdgcn_mfma_f32_16x16x32_f16(Aa[kc], B.h, ca, 0, 0, 0);
            cz = __builtin_amdgcn_mfma_f32_16x16x32_f16(Az[kc], B.h, cz, 0, 0, 0);
        }

        // ---- C layout: col = l&15, row = (l>>4)*4 + r  -> stash per wave
        #pragma unroll
        for (int r = 0; r < 4; ++r) {
            red[wv][kg * 4 + r][l & 15]      = ca[r];
            red[wv][16 + kg * 4 + r][l & 15] = cz[r];
        }
        __syncthreads();

        // ---- gates + state update (128 threads)
        if (tid < 128) {
            float sa = 0.f, sz = 0.f;
            #pragma unroll
            for (int v = 0; v < 8; ++v) {
                sa += red[v][jl][bl];
                sz += red[v][16 + jl][bl];
            }
            float at = wa + sa;
            float zt = wz + sz;
            zt = 1.f / (1.f + expf(-zt));
            float hc = tanhf(at);
            float hnew = zt * hprev + (1.f - zt) * hc;
            hprev = hnew;
            int bg = bg0 + bl;
            out[((size_t)bg * TLEN + t) * HID + j0 + jl] = hnew;   // plain
            if (t < TLEN - 1) {
                // pack fp16 pair with jl^1 partner, one 4B coherent store
                unsigned short hv =
                    __builtin_bit_cast(unsigned short, (_Float16)hnew);
                unsigned int other = __shfl_xor((unsigned int)hv, 1);
                if ((jl & 1) == 0) {
                    unsigned int packed = (unsigned int)hv | (other << 16);
                    st_h32((unsigned int*)&h_n[(size_t)bg * HID + j0 + jl],
                           packed);
                }
            } else {
                hlast[(size_t)bg * HID + j0 + jl] = hnew;
            }
        }

        // ---- publish: one store; 3-deep ring makes WAR free
        if (t < TLEN - 1) {
            __syncthreads();   // drains vmcnt -> h stores at LLC
            if (tid == 0) st_flag(&flags[wg * FSTRIDE], t + 1);
        }

        unsigned short* tmp = h_t; h_t = h_n; h_n = h_p; h_p = tmp;
    }
}

// ---------------------------------------------------------------------------
extern "C" void kernel_launch(void* const* d_in, const int* in_sizes, int n_in,
                              void* d_out, int out_size, void* d_ws, size_t ws_size,
                              hipStream_t stream) {
    (void)in_sizes; (void)n_in; (void)out_size; (void)ws_size;

    const float* x  = (const float*)d_in[0];
    const float* W0 = (const float*)d_in[1];
    const float* U0 = (const float*)d_in[2];
    const float* W1 = (const float*)d_in[3];
    const float* U1 = (const float*)d_in[4];

    float* out    = (float*)d_out;                              // [B,T,H]
    float* hstack = out + (size_t)BATCH * TLEN * HID;           // [2,B,H]

    int*            flags = (int*)d_ws;                         // 16 KB
    unsigned short* hring = (unsigned short*)(flags + NWG * FSTRIDE); // [3][B][H] fp16
    float*          wbuf  = (float*)(hring + 3 * BHID);         // [T][B][2H]

    dim3 gg(16384 / 128, 2048 / 128);
    int init_blocks = (BHID + 255) / 256;                       // covers flags too

    // ---- layer 0 ----
    proj_gemm<<<gg, 256, 0, stream>>>(x, W0, wbuf, 512);
    rec_init<<<init_blocks, 256, 0, stream>>>(hring, flags);
    ligru_rec<<<dim3(NWG), dim3(512), 0, stream>>>(wbuf, U0, hring, flags,
                                                   out, hstack);

    // ---- layer 1 ---- (reads layer-0 output staged in d_out, then overwrites)
    proj_gemm<<<gg, 256, 0, stream>>>(out, W1, wbuf, 1024);
    rec_init<<<init_blocks, 256, 0, stream>>>(hring, flags);
    ligru_rec<<<dim3(NWG), dim3(512), 0, stream>>>(wbuf, U1, hring, flags,
                                                   out, hstack + BATCH * HID);
}